// Round 8
// baseline (98.142 us; speedup 1.0000x reference)
//
#include <hip/hip_runtime.h>
#include <math.h>
#include <stdint.h>

// ---------------------------------------------------------------------------
// TemporalRelationGraph forward, MI355X — bf16 MFMA pipeline, round 8
// B=256, SEQ=8, NOBJ=10, SD=256, K=3, D=1024, NB=512, NC=174
//   gram_var     : per-batch S = F F^T via bf16 hi/lo-split MFMA, xsum fused,
//                  S-based power iteration, softmax, tail -> Rbf bf16 (2048x1024)
//   prep_weights : W1 -> W1T bf16 [10][512][1024], W2 -> W2T [192][2048]
//   p_mfma       : SPARSE-ROW P GEMM — per slice (s,j) only rows with
//                  t in [lo_sl, lo_sl+len_sl) are ever read by hsum
//                  (51/80 row-slices = 64% of dense work). P slice-packed
//                  [256*len][512] bf16, 13.4 MB. Grid 408 blocks, XCD-swizzled.
//   hsum_all     : Hsum(2048x2048 bf16) windowed relu-sums, short4-widened
//   out_split    : split-K=4 partials f32; out_reduce: sum + counted biases
// Train/test plans identical for SEQ=8,NF=4,SUB=10 -> is_test ignored.
// ---------------------------------------------------------------------------

typedef __attribute__((ext_vector_type(8))) short short8v;
typedef __attribute__((ext_vector_type(4))) short short4v;
typedef __attribute__((ext_vector_type(4))) float f32x4;

__device__ __forceinline__ short f2bf(float f) {
  uint32_t u = __float_as_uint(f);
  u += 0x7fffu + ((u >> 16) & 1u);      // RNE
  return (short)(u >> 16);
}
__device__ __forceinline__ float bf2f(short s) {
  return __uint_as_float(((uint32_t)(uint16_t)s) << 16);
}
__device__ __forceinline__ void gload16(const void* g, void* l) {
  __builtin_amdgcn_global_load_lds(
      (const __attribute__((address_space(1))) void*)g,
      (__attribute__((address_space(3))) void*)l, 16, 0, 0);
}

__device__ const int8_t ROWS4[12][5] = {
  {3, 0,1,2,3},
  {4, 0,1,2,3},{4, 1,2,3,4},
  {5, 0,1,2,3},{5, 1,2,3,4},{5, 2,3,4,5},
  {6, 0,1,2,3},{6, 1,2,3,4},{6, 2,3,4,5},{6, 3,4,5,6},
  {7, 0,2,4,6},{7, 1,3,5,7},
};
__device__ const int8_t ROWS3[15][4] = {
  {2, 0,1,2},
  {3, 0,1,2},{3, 1,2,3},
  {4, 0,1,2},{4, 1,2,3},{4, 2,3,4},
  {5, 0,2,4},{5, 1,3,5},
  {6, 0,2,4},{6, 1,3,5},{6, 2,4,6},
  {7, 0,2,4},{7, 1,3,5},{7, 2,4,6},{7, 3,5,7},
};
__device__ const int8_t ROWS2[19][3] = {
  {1, 0,1},
  {2, 0,1},{2, 1,2},
  {3, 0,2},{3, 1,3},
  {4, 0,2},{4, 1,3},{4, 2,4},
  {5, 0,3},{5, 1,4},{5, 2,5},
  {6, 0,3},{6, 1,4},{6, 2,5},{6, 3,6},
  {7, 0,4},{7, 1,5},{7, 2,6},{7, 3,7},
};
__device__ const int8_t ROWS1[36][2] = {
  {0,0},
  {1,0},{1,1},
  {2,0},{2,1},{2,2},
  {3,0},{3,1},{3,2},{3,3},
  {4,0},{4,1},{4,2},{4,3},{4,4},
  {5,0},{5,1},{5,2},{5,3},{5,4},{5,5},
  {6,0},{6,1},{6,2},{6,3},{6,4},{6,5},{6,6},
  {7,0},{7,1},{7,2},{7,3},{7,4},{7,5},{7,6},{7,7},
};
// window counts per (t, scale-index): si 0->s4, 1->s3, 2->s2, 3->s1
__device__ const float CNT[8][4] = {
  {0,0,0,1},{0,0,1,2},{0,1,2,3},{1,2,2,4},
  {2,3,3,5},{3,2,3,6},{4,3,4,7},{2,4,4,8},
};

// sparse-P slice tables: slices 0-3 = s4 j0-3, 4-6 = s3, 7-8 = s2, 9 = s1
__device__ const int SL_LO[10]  = {0,1,2,3, 0,1,2, 0,1, 0};
__device__ const int SL_LEN[10] = {4,4,4,5, 4,5,6, 4,7, 8};
__device__ const int SL_PB[10]  = {0,4,8,12,17,21,26,32,36,43};  // x 131072 shorts
__device__ const int SL_MT[10]  = {0,8,16,24,34,42,52,64,72,86}; // m-tile starts (102 total)

// LDS offsets (bytes) for gram_var
#define GV_FH    0
#define GV_FL    20480
#define GV_S     40960
#define GV_XSUM  67840
#define GV_VB    76032
#define GV_UU    78048
#define GV_SCAL  79008
#define GV_SZ    79056

// ---------------------------------------------------------------------------
// One block per batch, 256 threads (4 waves).
__global__ __launch_bounds__(256) void gram_var(
    const float* __restrict__ init, const float* __restrict__ graph,
    short* __restrict__ Rbuf)
{
  __shared__ __align__(16) char smem[GV_SZ];
  short* Fh  = (short*)(smem + GV_FH);
  short* Fl  = (short*)(smem + GV_FL);
  float* Sm  = (float*)(smem + GV_S);
  float* xsm = (float*)(smem + GV_XSUM);
  float* vb  = (float*)(smem + GV_VB);
  float* uum = (float*)(smem + GV_UU);
  float* scal= (float*)(smem + GV_SCAL);

  const int tid = threadIdx.x, lane = tid & 63, w = tid >> 6;
  const int b = blockIdx.x;
  const float* fb = init + (size_t)b * 80 * 256;

  int ti_[7], tj_[7];
#pragma unroll
  for (int q = 0; q < 7; ++q) {
    int tt = w + q * 4;
    int t5 = (tt < 25) ? tt : 0;
    ti_[q] = t5 / 5; tj_[q] = t5 % 5;
  }

  f32x4 acc[7];
#pragma unroll
  for (int q = 0; q < 7; ++q) acc[q] = (f32x4){0.f, 0.f, 0.f, 0.f};

  for (int ch = 0; ch < 2; ++ch) {
    __syncthreads();
    {
      const int t = tid >> 5, kq = tid & 31;
      const float* src = fb + (size_t)(t * 10) * 256 + ch * 128 + kq * 4;
      f32x4 sum = (f32x4){0.f, 0.f, 0.f, 0.f};
#pragma unroll
      for (int o = 0; o < 10; ++o) {
        f32x4 v = *(const f32x4*)(src + (size_t)o * 256);
        int r = t * 10 + o;
        int byte8 = r * 256 + ((kq * 8) ^ ((r & 7) << 4));
        short4v hv, lv;
#pragma unroll
        for (int e = 0; e < 4; ++e) {
          short h = f2bf(v[e]);
          hv[e] = h;
          lv[e] = f2bf(v[e] - bf2f(h));
        }
        *(short4v*)((char*)Fh + byte8) = hv;
        *(short4v*)((char*)Fl + byte8) = lv;
        sum += v;
      }
      *(f32x4*)(xsm + t * 256 + ch * 128 + kq * 4) = sum;
    }
    __syncthreads();

#pragma unroll
    for (int ks = 0; ks < 4; ++ks) {
      const int koff2 = (ks * 32 + (lane >> 4) * 8) * 2;
#pragma unroll
      for (int q = 0; q < 7; ++q) {
        const int tt = w + q * 4;
        if (tt < 25) {
          int ra = ti_[q] * 16 + (lane & 15);
          int rb = tj_[q] * 16 + (lane & 15);
          int ba = ra * 256 + (koff2 ^ ((ra & 7) << 4));
          int bb = rb * 256 + (koff2 ^ ((rb & 7) << 4));
          short8v ah = *(const short8v*)((char*)Fh + ba);
          short8v al = *(const short8v*)((char*)Fl + ba);
          short8v bh = *(const short8v*)((char*)Fh + bb);
          short8v bl = *(const short8v*)((char*)Fl + bb);
          acc[q] = __builtin_amdgcn_mfma_f32_16x16x32_bf16(ah, bh, acc[q], 0, 0, 0);
          acc[q] = __builtin_amdgcn_mfma_f32_16x16x32_bf16(ah, bl, acc[q], 0, 0, 0);
          acc[q] = __builtin_amdgcn_mfma_f32_16x16x32_bf16(al, bh, acc[q], 0, 0, 0);
        }
      }
    }
  }

#pragma unroll
  for (int q = 0; q < 7; ++q) {
    const int tt = w + q * 4;
    if (tt < 25) {
      int row0 = ti_[q] * 16 + (lane >> 4) * 4;
      int col = tj_[q] * 16 + (lane & 15);
#pragma unroll
      for (int r = 0; r < 4; ++r) Sm[(row0 + r) * 84 + col] = acc[q][r];
    }
  }
  if (tid < 240) vb[(0 * 3 + tid / 80) * 84 + (tid % 80)] = 1.0f;
  __syncthreads();

  const int pk = (tid < 240) ? tid / 80 : 0;
  const int pi = (tid < 240) ? tid % 80 : 0;
  int cur = 0;
  for (int it = 0; it < 5; ++it) {
    const bool last = (it == 4);
    float u = 0.f;
    if (tid < 240) {
      const float* Si = Sm + pi * 84;
      const float* vk = vb + (cur * 3 + pk) * 84;
#pragma unroll
      for (int q2 = 0; q2 < 20; ++q2) {
        f32x4 aa = *(const f32x4*)(Si + q2 * 4);
        f32x4 vv = *(const f32x4*)(vk + q2 * 4);
        u += aa.x * vv.x + aa.y * vv.y + aa.z * vv.z + aa.w * vv.w;
      }
    } else if (tid < 246) {
      int w2 = tid - 240;
      int k = (w2 < 3) ? w2 : w2 - 3;
      const float* vk = vb + (cur * 3 + k) * 84;
      float s = 0.f;
      if (w2 < 3) {
        for (int j2 = 0; j2 < 80; ++j2) s += vk[j2];
        scal[k] = s;
      } else {
        const float* Sk = Sm + k * 84;
        for (int j2 = 0; j2 < 80; ++j2) s += Sk[j2] * vk[j2];
        scal[3 + k] = s;
      }
    }
    __syncthreads();
    if (tid < 240) {
      float sg = scal[pk], tu = scal[3 + pk];
      float un = u - Sm[pi * 84 + pk] * sg - tu + Sm[pk * 84 + pk] * sg;
      if (!last) vb[((cur ^ 1) * 3 + pk) * 84 + pi] = un * 6.103515625e-05f;
      else       uum[pk * 80 + pi] = un;
    }
    __syncthreads();
    if (!last) cur ^= 1;
  }

  if (tid < 192) {
    const int k = tid >> 6, ln = tid & 63;
    float v1 = vb[(cur * 3 + k) * 84 + ln];
    float u1 = uum[k * 80 + ln];
    float a = u1 * v1, b2 = v1 * v1;
    if (ln < 16) {
      float v2 = vb[(cur * 3 + k) * 84 + 64 + ln];
      float u2 = uum[k * 80 + 64 + ln];
      a += u2 * v2; b2 += v2 * v2;
    }
#pragma unroll
    for (int m = 32; m >= 1; m >>= 1) {
      a += __shfl_xor(a, m);
      b2 += __shfl_xor(b2, m);
    }
    if (ln == 0) scal[9 + k] = a / b2;
  }
  __syncthreads();
  if (tid == 0) {
    float L0 = -0.1f * scal[9], L1 = -0.1f * scal[10], L2 = -0.1f * scal[11];
    float m = fmaxf(L0, fmaxf(L1, L2));
    float e0 = expf(L0 - m), e1 = expf(L1 - m), e2 = expf(L2 - m);
    float inv = 1.0f / (e0 + e1 + e2);
    scal[6] = e0 * inv; scal[7] = e1 * inv; scal[8] = e2 * inv;
  }
  __syncthreads();

  {
    const float w0 = scal[6], w1 = scal[7], w2 = scal[8];
    const int d0 = (tid & 63) * 4;
#pragma unroll
    for (int p = 0; p < 2; ++p) {
      const int t = p * 4 + (tid >> 6);
      f32x4 xs = *(const f32x4*)(xsm + t * 256 + d0);
      f32x4 c0 = *(const f32x4*)(fb + 0 * 256 + d0);
      f32x4 c1 = *(const f32x4*)(fb + 1 * 256 + d0);
      f32x4 c2 = *(const f32x4*)(fb + 2 * 256 + d0);
      f32x4 go = *(const f32x4*)(graph + (size_t)(b * 8 + t) * 256 + d0);
      size_t rb = ((size_t)(b * 8 + t)) * 1024;
      short4v s0, s1, s2, s3;
#pragma unroll
      for (int q = 0; q < 4; ++q) {
        float xq = xs[q];
        s0[q] = f2bf(fmaxf(w0 * (xq - 10.f * c0[q]), 0.f));
        s1[q] = f2bf(fmaxf(w1 * (xq - 10.f * c1[q]), 0.f));
        s2[q] = f2bf(fmaxf(w2 * (xq - 10.f * c2[q]), 0.f));
        s3[q] = f2bf(fmaxf(go[q], 0.f));
      }
      *(short4v*)&Rbuf[rb + 0 + d0]   = s0;
      *(short4v*)&Rbuf[rb + 256 + d0] = s1;
      *(short4v*)&Rbuf[rb + 512 + d0] = s2;
      *(short4v*)&Rbuf[rb + 768 + d0] = s3;
    }
  }
}

// ---------------------------------------------------------------------------
// blocks [0,1280): W1 64x64 transpose tiles (LDS stride 65 -> 2-way, free);
// blocks [1280,1472): W2T build.
__global__ __launch_bounds__(512) void prep_weights(
    const float* __restrict__ w1_4, const float* __restrict__ w1_3,
    const float* __restrict__ w1_2, const float* __restrict__ w1_1,
    const float* __restrict__ w2a, const float* __restrict__ w2b,
    const float* __restrict__ w2c, const float* __restrict__ w2d,
    short* __restrict__ W1T, short* __restrict__ W2T)
{
  __shared__ float sh[64 * 65];
  const int blk = blockIdx.x, tid = threadIdx.x;
  if (blk < 1280) {
    const int slice = blk >> 7, rem = blk & 127;
    const int k0 = (rem & 15) * 64, c0 = (rem >> 4) * 64;
    const float* W1; int j;
    if (slice < 4)      { W1 = w1_4; j = slice; }
    else if (slice < 7) { W1 = w1_3; j = slice - 4; }
    else if (slice < 9) { W1 = w1_2; j = slice - 7; }
    else                { W1 = w1_1; j = 0; }
#pragma unroll
    for (int q = tid; q < 1024; q += 512) {
      int r = q >> 4, cq = (q & 15) * 4;
      f32x4 v = *(const f32x4*)(W1 + (size_t)(j * 1024 + k0 + r) * 512 + c0 + cq);
      sh[r * 65 + cq + 0] = v.x; sh[r * 65 + cq + 1] = v.y;
      sh[r * 65 + cq + 2] = v.z; sh[r * 65 + cq + 3] = v.w;
    }
    __syncthreads();
#pragma unroll
    for (int q = tid; q < 1024; q += 512) {
      int cc = q >> 4, kq = (q & 15) * 4;
      short4v sv;
#pragma unroll
      for (int m = 0; m < 4; ++m) sv[m] = f2bf(sh[(kq + m) * 65 + cc]);
      *(short4v*)&W1T[(size_t)(slice * 512 + c0 + cc) * 1024 + k0 + kq] = sv;
    }
  } else {
    int idx = (blk - 1280) * 2048 + tid * 4;
    int col = idx >> 11, kg = idx & 2047;
    int si = kg >> 9, kr = kg & 511;
    const float* w = (si == 0) ? w2a : (si == 1) ? w2b : (si == 2) ? w2c : w2d;
    short4v sv;
#pragma unroll
    for (int q = 0; q < 4; ++q)
      sv[q] = (col < 174) ? f2bf(w[(size_t)(kr + q) * 174 + col]) : (short)0;
    *(short4v*)&W2T[idx] = sv;
  }
}

// ---------------------------------------------------------------------------
// Sparse-row P GEMM. Block -> (slice sl, m-tile mt, col-tile ctile).
// Local row lr maps to R row gr = (lr/len)*8 + lo + lr%len.
// Pp (slice-packed) stride 512. Grid 408 = 8*51, XCD-bijective swizzle.
__global__ __launch_bounds__(256) void p_mfma(
    const short* __restrict__ A, const short* __restrict__ W1T,
    short* __restrict__ P)
{
  __shared__ short As[128 * 32];
  __shared__ short Bs[128 * 32];
  const int id = blockIdx.x;
  const int nid = (id & 7) * 51 + (id >> 3);       // 408 = 8 XCD * 51
  const int ctile = nid & 3;
  const int rest = nid >> 2;                       // 0..101
  int sl = 0;
#pragma unroll
  for (int q = 1; q < 10; ++q) if (rest >= SL_MT[q]) sl = q;
  const int mt = rest - SL_MT[sl];
  const int lo = SL_LO[sl];
  const unsigned len = (unsigned)SL_LEN[sl];
  short* Pp = P + (size_t)SL_PB[sl] * 131072;
  const short* Bp = W1T + ((size_t)sl * 512 + (size_t)ctile * 128) * 1024;

  const int tid = threadIdx.x, lane = tid & 63, w = tid >> 6;
  const int wr = w >> 1, wc = w & 1;
  const int rA = w * 16 + (lane >> 2);
  const int kkA = (lane & 3) * 8;
  const unsigned lr0 = (unsigned)(mt * 128 + rA), lr1 = lr0 + 64u;
  const int gr0 = (int)((lr0 / len) * 8u + lo + (lr0 % len));
  const int gr1 = (int)((lr1 / len) * 8u + lo + (lr1 % len));

  f32x4 acc[4][4];
#pragma unroll
  for (int m = 0; m < 4; ++m)
#pragma unroll
    for (int n = 0; n < 4; ++n) acc[m][n] = (f32x4){0.f, 0.f, 0.f, 0.f};

  for (int k0 = 0; k0 < 1024; k0 += 32) {
    __syncthreads();
    gload16(A + (size_t)gr0 * 1024 + k0 + kkA, As + w * 512);
    gload16(A + (size_t)gr1 * 1024 + k0 + kkA, As + 2048 + w * 512);
    gload16(Bp + (size_t)rA * 1024 + k0 + kkA, Bs + w * 512);
    gload16(Bp + (size_t)(64 + rA) * 1024 + k0 + kkA, Bs + 2048 + w * 512);
    __syncthreads();
    short8v a[4], bv[4];
#pragma unroll
    for (int m = 0; m < 4; ++m)
      a[m] = *(const short8v*)(As + (wr * 64 + m * 16 + (lane & 15)) * 32 + (lane >> 4) * 8);
#pragma unroll
    for (int n = 0; n < 4; ++n)
      bv[n] = *(const short8v*)(Bs + (wc * 64 + n * 16 + (lane & 15)) * 32 + (lane >> 4) * 8);
#pragma unroll
    for (int m = 0; m < 4; ++m)
#pragma unroll
      for (int n = 0; n < 4; ++n)
        acc[m][n] = __builtin_amdgcn_mfma_f32_16x16x32_bf16(a[m], bv[n], acc[m][n], 0, 0, 0);
  }

#pragma unroll
  for (int m = 0; m < 4; ++m) {
    int lrow = mt * 128 + wr * 64 + m * 16 + (lane >> 4) * 4;
#pragma unroll
    for (int n = 0; n < 4; ++n) {
      int col = ctile * 128 + wc * 64 + n * 16 + (lane & 15);
#pragma unroll
      for (int r = 0; r < 4; ++r)
        Pp[(size_t)(lrow + r) * 512 + col] = f2bf(acc[m][n][r]);
    }
  }
}

// ---------------------------------------------------------------------------
// Hsum[row][si*512+c] bf16; 2 rows/block (wave-split), short4 loads from
// slice-packed P. Per-slice constants folded at compile time.
__global__ __launch_bounds__(256) void hsum_all(
    const short* __restrict__ P,
    const float* __restrict__ b1a, const float* __restrict__ b1b,
    const float* __restrict__ b1c, const float* __restrict__ b1d,
    short* __restrict__ Hsum)
{
  const int tid = threadIdx.x;
  const int row = blockIdx.x * 2 + (tid >> 7);
  const int t = row & 7;
  const size_t bq = (size_t)(row >> 3);
  const int c0 = (tid & 127) * 4;

  {  // si=0, s=4: slices 0..3
    const int pb[4] = {0, 4 * 131072, 8 * 131072, 12 * 131072};
    const int lo[4] = {0, 1, 2, 3};
    const int ln[4] = {4, 4, 4, 5};
    f32x4 bb = *(const f32x4*)(b1a + c0);
    f32x4 a = (f32x4){0.f, 0.f, 0.f, 0.f};
    for (int r = 0; r < 12; ++r) {
      if (ROWS4[r][0] != t) continue;
      f32x4 h = bb;
#pragma unroll
      for (int jj = 0; jj < 4; ++jj) {
        const short4v pv = *(const short4v*)(P + pb[jj] +
            (bq * ln[jj] + (ROWS4[r][1 + jj] - lo[jj])) * 512 + c0);
#pragma unroll
        for (int e = 0; e < 4; ++e) h[e] += bf2f(pv[e]);
      }
#pragma unroll
      for (int e = 0; e < 4; ++e) a[e] += fmaxf(h[e], 0.f);
    }
    short4v sv;
#pragma unroll
    for (int e = 0; e < 4; ++e) sv[e] = f2bf(a[e]);
    *(short4v*)&Hsum[(size_t)row * 2048 + c0] = sv;
  }
  {  // si=1, s=3: slices 4..6
    const int pb[3] = {17 * 131072, 21 * 131072, 26 * 131072};
    const int lo[3] = {0, 1, 2};
    const int ln[3] = {4, 5, 6};
    f32x4 bb = *(const f32x4*)(b1b + c0);
    f32x4 a = (f32x4){0.f, 0.f, 0.f, 0.f};
    for (int r = 0; r < 15; ++r) {
      if (ROWS3[r][0] != t) continue;
      f32x4 h = bb;
#pragma unroll
      for (int jj = 0; jj < 3; ++jj) {
        const short4v pv = *(const short4v*)(P + pb[jj] +
            (bq * ln[jj] + (ROWS3[r][1 + jj] - lo[jj])) * 512 + c0);
#pragma unroll
        for (int e = 0; e < 4; ++e) h[e] += bf2f(pv[e]);
      }
#pragma unroll
      for (int e = 0; e < 4; ++e) a[e] += fmaxf(h[e], 0.f);
    }
    short4v sv;
#pragma unroll
    for (int e = 0; e < 4; ++e) sv[e] = f2bf(a[e]);
    *(short4v*)&Hsum[(size_t)row * 2048 + 512 + c0] = sv;
  }
  {  // si=2, s=2: slices 7..8
    const int pb[2] = {32 * 131072, 36 * 131072};
    const int lo[2] = {0, 1};
    const int ln[2] = {4, 7};
    f32x4 bb = *(const f32x4*)(b1c + c0);
    f32x4 a = (f32x4){0.f, 0.f, 0.f, 0.f};
    for (int r = 0; r < 19; ++r) {
      if (ROWS2[r][0] != t) continue;
      f32x4 h = bb;
#pragma unroll
      for (int jj = 0; jj < 2; ++jj) {
        const short4v pv = *(const short4v*)(P + pb[jj] +
            (bq * ln[jj] + (ROWS2[r][1 + jj] - lo[jj])) * 512 + c0);
#pragma unroll
        for (int e = 0; e < 4; ++e) h[e] += bf2f(pv[e]);
      }
#pragma unroll
      for (int e = 0; e < 4; ++e) a[e] += fmaxf(h[e], 0.f);
    }
    short4v sv;
#pragma unroll
    for (int e = 0; e < 4; ++e) sv[e] = f2bf(a[e]);
    *(short4v*)&Hsum[(size_t)row * 2048 + 1024 + c0] = sv;
  }
  {  // si=3, s=1: slice 9 (lo=0, len=8)
    f32x4 bb = *(const f32x4*)(b1d + c0);
    f32x4 a = (f32x4){0.f, 0.f, 0.f, 0.f};
    for (int r = 0; r < 36; ++r) {
      if (ROWS1[r][0] != t) continue;
      const short4v pv = *(const short4v*)(P + 43 * 131072 +
          (bq * 8 + ROWS1[r][1]) * 512 + c0);
#pragma unroll
      for (int e = 0; e < 4; ++e) a[e] += fmaxf(bb[e] + bf2f(pv[e]), 0.f);
    }
    short4v sv;
#pragma unroll
    for (int e = 0; e < 4; ++e) sv[e] = f2bf(a[e]);
    *(short4v*)&Hsum[(size_t)row * 2048 + 1536 + c0] = sv;
  }
}

// ---------------------------------------------------------------------------
// Split-K out GEMM: partial[z][2048][192] = Hsum[:, z*512:(z+1)*512] @ W2T^T.
__global__ __launch_bounds__(256) void out_split(
    const short* __restrict__ H, const short* __restrict__ W2T,
    float* __restrict__ partial)
{
  __shared__ short As[128 * 32];
  __shared__ short Bs[64 * 32];
  const int tid = threadIdx.x, lane = tid & 63, w = tid >> 6;
  const int wr = w >> 1, wc = w & 1;
  const int rowBase = blockIdx.y * 128, colBase = blockIdx.x * 64;
  const int kBase = blockIdx.z * 512;
  const int rA = w * 16 + (lane >> 2);
  const int kkA = (lane & 3) * 8;

  f32x4 acc[4][2];
#pragma unroll
  for (int m = 0; m < 4; ++m)
#pragma unroll
    for (int n = 0; n < 2; ++n) acc[m][n] = (f32x4){0.f, 0.f, 0.f, 0.f};

  for (int k0 = 0; k0 < 512; k0 += 32) {
    const int kg = kBase + k0;
    __syncthreads();
    gload16(H + (size_t)(rowBase + rA) * 2048 + kg + kkA, As + w * 512);
    gload16(H + (size_t)(rowBase + 64 + rA) * 2048 + kg + kkA, As + 2048 + w * 512);
    gload16(W2T + (size_t)(colBase + rA) * 2048 + kg + kkA, Bs + w * 512);
    __syncthreads();
    short8v a[4], bv[2];
#pragma unroll
    for (int m = 0; m < 4; ++m)
      a[m] = *(const short8v*)(As + (wr * 64 + m * 16 + (lane & 15)) * 32 + (lane >> 4) * 8);
#pragma unroll
    for (int n = 0; n < 2; ++n)
      bv[n] = *(const short8v*)(Bs + (wc * 32 + n * 16 + (lane & 15)) * 32 + (lane >> 4) * 8);
#pragma unroll
    for (int m = 0; m < 4; ++m)
#pragma unroll
      for (int n = 0; n < 2; ++n)
        acc[m][n] = __builtin_amdgcn_mfma_f32_16x16x32_bf16(a[m], bv[n], acc[m][n], 0, 0, 0);
  }

  float* pz = partial + (size_t)blockIdx.z * 2048 * 192;
#pragma unroll
  for (int n = 0; n < 2; ++n) {
    int col = colBase + wc * 32 + n * 16 + (lane & 15);
#pragma unroll
    for (int m = 0; m < 4; ++m) {
      int row0 = rowBase + wr * 64 + m * 16 + (lane >> 4) * 4;
#pragma unroll
      for (int r = 0; r < 4; ++r)
        pz[(size_t)(row0 + r) * 192 + col] = acc[m][n][r];
    }
  }
}

// ---------------------------------------------------------------------------
__global__ __launch_bounds__(256) void out_reduce(
    const float* __restrict__ partial,
    const float* __restrict__ b2a, const float* __restrict__ b2b,
    const float* __restrict__ b2c, const float* __restrict__ b2d,
    float* __restrict__ out)
{
  const int row = blockIdx.x, col = threadIdx.x;
  if (col >= 174) return;
  const size_t o = (size_t)row * 192 + col;
  float s = partial[o] + partial[o + (size_t)2048 * 192]
          + partial[o + (size_t)4096 * 192] + partial[o + (size_t)6144 * 192];
  int tt = row & 7;
  float bias = CNT[tt][0] * b2a[col] + CNT[tt][1] * b2b[col]
             + CNT[tt][2] * b2c[col] + CNT[tt][3] * b2d[col];
  out[(size_t)row * 174 + col] = s + bias;
}

// ---------------------------------------------------------------------------
extern "C" void kernel_launch(void* const* d_in, const int* in_sizes, int n_in,
                              void* d_out, int out_size, void* d_ws, size_t ws_size,
                              hipStream_t stream) {
  const float* graph = (const float*)d_in[0];
  const float* init  = (const float*)d_in[1];
  const float* w1[4] = {(const float*)d_in[3],  (const float*)d_in[7],
                        (const float*)d_in[11], (const float*)d_in[15]};
  const float* b1[4] = {(const float*)d_in[4],  (const float*)d_in[8],
                        (const float*)d_in[12], (const float*)d_in[16]};
  const float* w2[4] = {(const float*)d_in[5],  (const float*)d_in[9],
                        (const float*)d_in[13], (const float*)d_in[17]};
  const float* b2[4] = {(const float*)d_in[6],  (const float*)d_in[10],
                        (const float*)d_in[14], (const float*)d_in[18]};
  float* out = (float*)d_out;

  char* ws = (char*)d_ws;
  short* Rbf  = (short*)(ws + 0);                    // 4 MiB   (dead after p_mfma)
  short* W1T  = (short*)(ws + ((size_t)4  << 20));   // 10 MiB  (dead after p_mfma)
  short* P    = (short*)(ws + ((size_t)14 << 20));   // 12.75 MiB (slice-packed)
  short* W2T  = (short*)(ws + ((size_t)34 << 20));   // 0.75 MiB
  short* Hsum = (short*)(ws + 0);                    // 8 MiB   (over Rbf/W1T head)
  float* Part = (float*)(ws + ((size_t)8 << 20));    // 6 MiB   (over W1T tail)

  gram_var<<<256, 256, 0, stream>>>(init, graph, Rbf);

  prep_weights<<<1472, 512, 0, stream>>>(w1[0], w1[1], w1[2], w1[3],
                                         w2[0], w2[1], w2[2], w2[3], W1T, W2T);

  p_mfma<<<408, 256, 0, stream>>>(Rbf, W1T, P);

  hsum_all<<<1024, 256, 0, stream>>>(P, b1[0], b1[1], b1[2], b1[3], Hsum);

  out_split<<<dim3(3, 16, 4), 256, 0, stream>>>(Hsum, W2T, Part);

  out_reduce<<<2048, 256, 0, stream>>>(Part, b2[0], b2[1], b2[2], b2[3], out);
}